// Round 4
// baseline (363.798 us; speedup 1.0000x reference)
//
#include <hip/hip_runtime.h>

#define BATCH 8192
#define DIM   2048   // IN_DIM == OUT_DIM
#define DEPTH 5

// ============================================================================
// GEMM geometry: block tile 256(M) x 128(N), BK=32, 512 threads = 8 waves
// (4 wm x 2 wn), wave tile 64x64 = 4x4 frags of 16x16x32 bf16 MFMA, bf16x3
// triple (hh, hl, lh) per frag pair -> 48 MFMA / wave / K-tile.
//
// LDS: 3-deep pipeline buffers. Per buffer:
//   A region: [hl(2)][256 rows][32 k] bf16 = 32 KB   (row = hl*256 + m_local)
//   B region: [hl(2)][128 rows][32 k] bf16 = 16 KB   (row = hl*128 + n_local)
//   -> 48 KB/buffer, 144 KB total (<= 160 KB gfx950 workgroup max).
//
// Swizzle (T2): physical byte = logical byte ^ (((row>>1)&3)<<4). 16-lane
// column reads then hit 8 distinct 16B granule-columns x 2 lanes = 2-way
// (free, m136). global_load_lds writes LDS linearly, so the swizzle is
// applied by permuting the per-lane GLOBAL source granule (rule 21):
//   logical k-granule = (p&3) ^ ((p>>3)&3) for physical granule p.
//
// Pipeline (T3/T4): while computing tile t (buf t%3), issue the 6
// global_load_lds for tile t+2 (buf (t+2)%3, last read as tile t-1 and
// fully consumed before t's barriers). Sync discipline (round-2 fix):
// vmcnt is PER-WAVE, so each wave waits vmcnt(6) at the END of iter t
// (retiring tile t+1's loads, its own) IMMEDIATELY BEFORE the iter-final
// s_barrier; wait+barrier = collective "tile t+1 landed" guarantee before
// any wave's iter-t+1 ds_reads. No vmcnt(0) drain in the steady loop.
// Raw asm s_barrier (memory clobber = compiler fence, no auto drain).
// setprio(1) around MFMA clusters (T5).
// ============================================================================

#define BUFSZ  49152
#define ABYTES 32768

typedef short bf16x8_t __attribute__((ext_vector_type(8)));
typedef float f32x4_t  __attribute__((ext_vector_type(4)));

// ---- bf16 split helpers (RNE, bit-manip) ----
__device__ __forceinline__ unsigned short f2bf(float f) {
  unsigned u = __float_as_uint(f);
  u += 0x7fffu + ((u >> 16) & 1u);
  return (unsigned short)(u >> 16);
}
__device__ __forceinline__ float bf2f(unsigned short h) {
  return __uint_as_float(((unsigned)h) << 16);
}

// ============================================================================
// Fused prep (one dispatch):
//  blocks [0, 8192)      : split x -> xhi/xlo, row-major [8192][2048] bf16
//  blocks [8192, 12288)  : W (KxN) -> transpose+split -> whi/wlo [N][K] bf16
//  blocks [12288, 12296) : bias2[j] = b[j] + (1/2048)*prod_d cos(hdw[d,j,0])^2
// ============================================================================
__global__ void prep_fused_kernel(const float* __restrict__ x,
                                  const float* __restrict__ hdw,
                                  const float* __restrict__ W,
                                  const float* __restrict__ bias,
                                  float* __restrict__ bias2,
                                  unsigned short* __restrict__ xhi,
                                  unsigned short* __restrict__ xlo,
                                  unsigned short* __restrict__ whi,
                                  unsigned short* __restrict__ wlo) {
  __shared__ float tile[32][33];
  const int b = blockIdx.x;
  const int tid = threadIdx.x;

  if (b < 8192) {  // ---- split x, row-major ----
    size_t g = (size_t)b * 256 + tid;       // 8-elem chunk id
    const float4* xp = (const float4*)(x + g * 8);
    float4 v0 = xp[0], v1 = xp[1];
    float v[8] = {v0.x, v0.y, v0.z, v0.w, v1.x, v1.y, v1.z, v1.w};
    bf16x8_t h, lo;
#pragma unroll
    for (int j = 0; j < 8; ++j) {
      unsigned short hj = f2bf(v[j]);
      h[j] = (short)hj;
      lo[j] = (short)f2bf(v[j] - bf2f(hj));
    }
    ((bf16x8_t*)xhi)[g] = h;
    ((bf16x8_t*)xlo)[g] = lo;
  } else if (b < 12288) {  // ---- transpose + split W -> [N][K] ----
    const int t = b - 8192;          // 4096 tiles of 32x32
    const int k0 = (t >> 6) * 32;
    const int n0 = (t & 63) * 32;
    const int tx = tid & 31;   // n within tile
    const int ty = tid >> 5;   // k within tile (8 rows/iter)
#pragma unroll
    for (int r = 0; r < 32; r += 8)
      tile[ty + r][tx] = W[(size_t)(k0 + ty + r) * DIM + n0 + tx];
    __syncthreads();
    const int n = tid >> 3;          // 0..31
    const int kq = (tid & 7) * 4;    // 0..28
    ushort4 hv, lv;
    float vv0 = tile[kq + 0][n], vv1 = tile[kq + 1][n];
    float vv2 = tile[kq + 2][n], vv3 = tile[kq + 3][n];
    hv.x = f2bf(vv0); lv.x = f2bf(vv0 - bf2f(hv.x));
    hv.y = f2bf(vv1); lv.y = f2bf(vv1 - bf2f(hv.y));
    hv.z = f2bf(vv2); lv.z = f2bf(vv2 - bf2f(hv.z));
    hv.w = f2bf(vv3); lv.w = f2bf(vv3 - bf2f(hv.w));
    const size_t o = (size_t)(n0 + n) * DIM + k0 + kq;
    *(ushort4*)(whi + o) = hv;
    *(ushort4*)(wlo + o) = lv;
  } else {  // ---- bias2 (scan preserves axis-1 uniformity -> rolls cancel) ----
    int j = (b - 12288) * 256 + tid;
    float p = 1.0f;
#pragma unroll
    for (int d = 0; d < DEPTH; ++d)
      p *= cosf(hdw[(size_t)d * DIM * DIM + (size_t)j * DIM]);
    bias2[j] = bias[j] + p * p * (1.0f / 2048.0f);
  }
}

// ---- async global->LDS, 16B per lane, LDS dest = wave-uniform base + lane*16
#define GLDS(SRC, OFF)                                                         \
  __builtin_amdgcn_global_load_lds(                                            \
      (const __attribute__((address_space(1))) unsigned int*)(SRC),            \
      (__attribute__((address_space(3))) unsigned int*)(smem + (OFF)), 16, 0, 0)

#define MFMA16(A, B, C) __builtin_amdgcn_mfma_f32_16x16x32_bf16((A), (B), (C), 0, 0, 0)

__global__ __launch_bounds__(512, 2) void gemm_pipe_kernel(
    const unsigned short* __restrict__ Ah, const unsigned short* __restrict__ Al,
    const unsigned short* __restrict__ Bh, const unsigned short* __restrict__ Bl,
    const float* __restrict__ bias2, float* __restrict__ out) {
  __shared__ float4 smem4[3 * BUFSZ / 16];
  char* smem = (char*)smem4;

  const int tid  = threadIdx.x;
  const int lane = tid & 63;
  const int wave = tid >> 6;
  const int wm   = wave >> 1;      // 0..3 : 64-row strip within 256
  const int wn   = wave & 1;       // 0..1 : 64-col strip within 128
  const int l15  = lane & 15;
  const int kl   = lane >> 4;
  const int bm = blockIdx.x;       // 32 strips of 256 rows
  const int bn = blockIdx.y;       // 16 strips of 128 cols

  // ---- per-lane staging sources (inverse-swizzled global granule) ----
  // Physical LDS granule for (inst i, wave, lane): p = i*512 + wave*64 + lane.
  // row = p>>2 -> rsub = wave*16 + (lane>>2); logical k-granule =
  // (p&3)^((p>>3)&3) = (lane&3)^((lane>>3)&3)  (i*512, wave*64 vanish mod 4).
  const int rsub = wave * 16 + (lane >> 2);                 // 0..127
  const int kg   = ((lane & 3) ^ ((lane >> 3) & 3)) * 8;    // element offset
  const unsigned short* sA0 = Ah + ((size_t)(bm * 256 +       rsub)) * DIM + kg;
  const unsigned short* sA1 = Ah + ((size_t)(bm * 256 + 128 + rsub)) * DIM + kg;
  const unsigned short* sA2 = Al + ((size_t)(bm * 256 +       rsub)) * DIM + kg;
  const unsigned short* sA3 = Al + ((size_t)(bm * 256 + 128 + rsub)) * DIM + kg;
  const unsigned short* sB0 = Bh + ((size_t)(bn * 128 +       rsub)) * DIM + kg;
  const unsigned short* sB1 = Bl + ((size_t)(bn * 128 +       rsub)) * DIM + kg;
  const unsigned wdst = wave * 1024;   // wave-uniform byte base within slot

  // ---- per-lane fragment read offset (matching swizzle) ----
  // A frag (mt,hl): byte = hl*16384 + (wm*64+mt*16)*64 + foff
  // B frag (nt,hl): byte = ABYTES + hl*8192 + (wn*64+nt*16)*64 + foff
  const int foff = l15 * 64 + ((kl * 16) ^ (((l15 >> 1) & 3) << 4));

  const f32x4_t vzero = {0.f, 0.f, 0.f, 0.f};
  f32x4_t acc[4][4];
#pragma unroll
  for (int i = 0; i < 4; ++i)
#pragma unroll
    for (int j = 0; j < 4; ++j) acc[i][j] = vzero;

  // ---- prologue: stage tile 0 -> buf0, tile 1 -> buf1 (6 loads each) ----
  GLDS(sA0,      0             + wdst);
  GLDS(sA1,      8192          + wdst);
  GLDS(sB0,      ABYTES        + wdst);
  GLDS(sA2,      16384         + wdst);
  GLDS(sA3,      24576         + wdst);
  GLDS(sB1,      ABYTES + 8192 + wdst);
  GLDS(sA0 + 32, BUFSZ + 0             + wdst);
  GLDS(sA1 + 32, BUFSZ + 8192          + wdst);
  GLDS(sB0 + 32, BUFSZ + ABYTES        + wdst);
  GLDS(sA2 + 32, BUFSZ + 16384         + wdst);
  GLDS(sA3 + 32, BUFSZ + 24576         + wdst);
  GLDS(sB1 + 32, BUFSZ + ABYTES + 8192 + wdst);

  // own tile-0 loads retired (6 newest = tile 1's), then collective barrier:
  // after this, ALL waves' tile-0 stores have landed in LDS.
  asm volatile("s_waitcnt vmcnt(6)" ::: "memory");
  asm volatile("s_barrier" ::: "memory");

#pragma unroll 1
  for (int t = 0; t < 64; ++t) {
    const unsigned bo = (unsigned)(t % 3) * BUFSZ;        // compute buffer
    const unsigned so = (unsigned)((t + 2) % 3) * BUFSZ;  // stage buffer
    const int ko = (t + 2) * 32;                          // stage src k-offset
    const bool st = (t < 62);

    // ---------------- phase A : mt 0,1  x  nt 0..3 ----------------
    bf16x8_t bh[4], bl[4], ah[2], al[2];
    const char* pB = smem + bo + ABYTES + wn * 4096 + foff;
#pragma unroll
    for (int nt = 0; nt < 4; ++nt) {
      bh[nt] = *(const bf16x8_t*)(pB + nt * 1024);
      bl[nt] = *(const bf16x8_t*)(pB + 8192 + nt * 1024);
    }
    const char* pA = smem + bo + wm * 4096 + foff;
    ah[0] = *(const bf16x8_t*)(pA);
    al[0] = *(const bf16x8_t*)(pA + 16384);
    ah[1] = *(const bf16x8_t*)(pA + 1024);
    al[1] = *(const bf16x8_t*)(pA + 16384 + 1024);
    if (st) {  // stage first half of tile t+2 (buf last read as tile t-1)
      GLDS(sA0 + ko, so + 0      + wdst);
      GLDS(sA1 + ko, so + 8192   + wdst);
      GLDS(sB0 + ko, so + ABYTES + wdst);
    }
    asm volatile("s_barrier" ::: "memory");
    __builtin_amdgcn_s_setprio(1);
#pragma unroll
    for (int i = 0; i < 2; ++i)
#pragma unroll
      for (int nt = 0; nt < 4; ++nt) {
        acc[i][nt] = MFMA16(ah[i], bh[nt], acc[i][nt]);
        acc[i][nt] = MFMA16(ah[i], bl[nt], acc[i][nt]);
        acc[i][nt] = MFMA16(al[i], bh[nt], acc[i][nt]);
      }
    __builtin_amdgcn_s_setprio(0);
    __builtin_amdgcn_sched_barrier(0);
    asm volatile("s_barrier" ::: "memory");

    // ---------------- phase B : mt 2,3  x  nt 0..3 ----------------
    bf16x8_t ah2[2], al2[2];
    ah2[0] = *(const bf16x8_t*)(pA + 2048);
    al2[0] = *(const bf16x8_t*)(pA + 16384 + 2048);
    ah2[1] = *(const bf16x8_t*)(pA + 3072);
    al2[1] = *(const bf16x8_t*)(pA + 16384 + 3072);
    if (st) {  // stage second half of tile t+2
      GLDS(sA2 + ko, so + 16384         + wdst);
      GLDS(sA3 + ko, so + 24576         + wdst);
      GLDS(sB1 + ko, so + ABYTES + 8192 + wdst);
    }
    asm volatile("s_barrier" ::: "memory");
    __builtin_amdgcn_s_setprio(1);
#pragma unroll
    for (int i = 0; i < 2; ++i)
#pragma unroll
      for (int nt = 0; nt < 4; ++nt) {
        acc[2 + i][nt] = MFMA16(ah2[i], bh[nt], acc[2 + i][nt]);
        acc[2 + i][nt] = MFMA16(ah2[i], bl[nt], acc[2 + i][nt]);
        acc[2 + i][nt] = MFMA16(al2[i], bh[nt], acc[2 + i][nt]);
      }
    __builtin_amdgcn_s_setprio(0);
    __builtin_amdgcn_sched_barrier(0);

    // ---- end-of-iter sync (the round-2 fix): each wave retires its OWN
    // tile-t+1 loads BEFORE the barrier; wait+barrier => all waves' tile-t+1
    // stores landed before anyone's iter-t+1 ds_reads. Never drains to 0
    // while staging continues.
    if (t < 62)       { asm volatile("s_waitcnt vmcnt(6)" ::: "memory"); }
    else if (t == 62) { asm volatile("s_waitcnt vmcnt(0)" ::: "memory"); }
    asm volatile("s_barrier" ::: "memory");
  }

  // ---- epilogue: C/D layout col = lane&15, row = (lane>>4)*4 + reg ----
  const int orow0 = bm * 256 + wm * 64;
  const int ocol0 = bn * 128 + wn * 64;
#pragma unroll
  for (int j = 0; j < 4; ++j) {
    const int col = ocol0 + j * 16 + l15;
    const float b2 = bias2[col];
#pragma unroll
    for (int i = 0; i < 4; ++i) {
      const int row = orow0 + i * 16 + kl * 4;
#pragma unroll
      for (int r = 0; r < 4; ++r) {
        float z = acc[i][j][r] + b2;
        // tanh(z) = 1 - 2/(exp(2z)+1)
        float e = __expf(2.0f * z);
        out[(size_t)(row + r) * DIM + col] = 1.0f - 2.0f / (e + 1.0f);
      }
    }
  }
}

// ============================================================================
extern "C" void kernel_launch(void* const* d_in, const int* in_sizes, int n_in,
                              void* d_out, int out_size, void* d_ws, size_t ws_size,
                              hipStream_t stream) {
  const float* x   = (const float*)d_in[0];
  const float* hdw = (const float*)d_in[1];
  const float* W   = (const float*)d_in[2];
  const float* b   = (const float*)d_in[3];
  float* out = (float*)d_out;

  // workspace layout (~80.01 MB)
  char* ws = (char*)d_ws;
  unsigned short* xhi  = (unsigned short*)ws;                    // 32 MB
  unsigned short* xlo  = xhi + (size_t)BATCH * DIM;              // 32 MB
  unsigned short* wThi = xlo + (size_t)BATCH * DIM;              // 8 MB
  unsigned short* wTlo = wThi + (size_t)DIM * DIM;               // 8 MB
  float*          bias2 = (float*)(wTlo + (size_t)DIM * DIM);    // 8 KB

  prep_fused_kernel<<<12296, 256, 0, stream>>>(
      x, hdw, W, b, bias2, xhi, xlo, wThi, wTlo);
  gemm_pipe_kernel<<<dim3(BATCH / 256, DIM / 128), 512, 0, stream>>>(
      xhi, xlo, wThi, wTlo, bias2, out);
}

// Round 7
// 355.801 us; speedup vs baseline: 1.0225x; 1.0225x over previous
//
#include <hip/hip_runtime.h>

#define BATCH 8192
#define DIM   2048   // IN_DIM == OUT_DIM
#define DEPTH 5

// ============================================================================
// GEMM geometry: block tile 256(M) x 128(N), BK=32, 512 threads = 8 waves
// (4 wm x 2 wn), wave tile 64x64 = 4x4 frags of 16x16x32 bf16 MFMA, bf16x3
// triple (hh, hl, lh) per frag pair -> 48 MFMA / wave / K-tile.
//
// LDS: 3-deep pipeline buffers, 48 KB each (A 32 KB + B 16 KB), 144 KB total.
// Swizzle (T2): physical byte = logical byte ^ (((row>>1)&3)<<4), applied via
// inverse-swizzled GLOBAL source granule (rule 21) + swizzled ds_read offset.
// Measured r4: SQ_LDS_BANK_CONFLICT = 0.
//
// Sync (round-5 restructure): ONE barrier per iteration. r4 measured 3917
// cyc/iter vs 1863 MFMA floor -- the 4 barriers/iter serialized ds_read and
// MFMA phases (m233's 2-phase stall). Hazard audit: (RAW) tile-t reads need
// all waves' tile-t GLDS landed -> prev iter's vmcnt(6)+barrier; (WAR) GLDS
// into buf (t+2)%3 needs all waves' tile-(t-1) reads done -> same barrier.
// Intra-wave ds_read->MFMA is lgkmcnt (compiler). So: issue 6 GLDS at iter
// top, ds_reads + 48 MFMA flow barrier-free (waves drift; MFMA of one wave
// hides LDS reads of another), single end-of-iter vmcnt(6)+s_barrier.
// Never drains vmcnt in steady loop (T4). setprio around MFMA (T5).
// ============================================================================

#define BUFSZ  49152
#define ABYTES 32768

typedef short bf16x8_t __attribute__((ext_vector_type(8)));
typedef float f32x4_t  __attribute__((ext_vector_type(4)));

// ---- bf16 split helpers (RNE, bit-manip) ----
__device__ __forceinline__ unsigned short f2bf(float f) {
  unsigned u = __float_as_uint(f);
  u += 0x7fffu + ((u >> 16) & 1u);
  return (unsigned short)(u >> 16);
}
__device__ __forceinline__ float bf2f(unsigned short h) {
  return __uint_as_float(((unsigned)h) << 16);
}

// ============================================================================
// Fused prep (one dispatch) -- unchanged from r4 (verified):
//  blocks [0, 8192)      : split x -> xhi/xlo, row-major [8192][2048] bf16
//  blocks [8192, 12288)  : W (KxN) -> transpose+split -> whi/wlo [N][K] bf16
//  blocks [12288, 12296) : bias2[j] = b[j] + (1/2048)*prod_d cos(hdw[d,j,0])^2
// ============================================================================
__global__ void prep_fused_kernel(const float* __restrict__ x,
                                  const float* __restrict__ hdw,
                                  const float* __restrict__ W,
                                  const float* __restrict__ bias,
                                  float* __restrict__ bias2,
                                  unsigned short* __restrict__ xhi,
                                  unsigned short* __restrict__ xlo,
                                  unsigned short* __restrict__ whi,
                                  unsigned short* __restrict__ wlo) {
  __shared__ float tile[32][33];
  const int b = blockIdx.x;
  const int tid = threadIdx.x;

  if (b < 8192) {  // ---- split x, row-major ----
    size_t g = (size_t)b * 256 + tid;       // 8-elem chunk id
    const float4* xp = (const float4*)(x + g * 8);
    float4 v0 = xp[0], v1 = xp[1];
    float v[8] = {v0.x, v0.y, v0.z, v0.w, v1.x, v1.y, v1.z, v1.w};
    bf16x8_t h, lo;
#pragma unroll
    for (int j = 0; j < 8; ++j) {
      unsigned short hj = f2bf(v[j]);
      h[j] = (short)hj;
      lo[j] = (short)f2bf(v[j] - bf2f(hj));
    }
    ((bf16x8_t*)xhi)[g] = h;
    ((bf16x8_t*)xlo)[g] = lo;
  } else if (b < 12288) {  // ---- transpose + split W -> [N][K] ----
    const int t = b - 8192;          // 4096 tiles of 32x32
    const int k0 = (t >> 6) * 32;
    const int n0 = (t & 63) * 32;
    const int tx = tid & 31;   // n within tile
    const int ty = tid >> 5;   // k within tile (8 rows/iter)
#pragma unroll
    for (int r = 0; r < 32; r += 8)
      tile[ty + r][tx] = W[(size_t)(k0 + ty + r) * DIM + n0 + tx];
    __syncthreads();
    const int n = tid >> 3;          // 0..31
    const int kq = (tid & 7) * 4;    // 0..28
    ushort4 hv, lv;
    float vv0 = tile[kq + 0][n], vv1 = tile[kq + 1][n];
    float vv2 = tile[kq + 2][n], vv3 = tile[kq + 3][n];
    hv.x = f2bf(vv0); lv.x = f2bf(vv0 - bf2f(hv.x));
    hv.y = f2bf(vv1); lv.y = f2bf(vv1 - bf2f(hv.y));
    hv.z = f2bf(vv2); lv.z = f2bf(vv2 - bf2f(hv.z));
    hv.w = f2bf(vv3); lv.w = f2bf(vv3 - bf2f(hv.w));
    const size_t o = (size_t)(n0 + n) * DIM + k0 + kq;
    *(ushort4*)(whi + o) = hv;
    *(ushort4*)(wlo + o) = lv;
  } else {  // ---- bias2 (scan preserves axis-1 uniformity -> rolls cancel) ----
    int j = (b - 12288) * 256 + tid;
    float p = 1.0f;
#pragma unroll
    for (int d = 0; d < DEPTH; ++d)
      p *= cosf(hdw[(size_t)d * DIM * DIM + (size_t)j * DIM]);
    bias2[j] = bias[j] + p * p * (1.0f / 2048.0f);
  }
}

// ---- async global->LDS, 16B per lane, LDS dest = wave-uniform base + lane*16
#define GLDS(SRC, OFF)                                                         \
  __builtin_amdgcn_global_load_lds(                                            \
      (const __attribute__((address_space(1))) unsigned int*)(SRC),            \
      (__attribute__((address_space(3))) unsigned int*)(smem + (OFF)), 16, 0, 0)

#define MFMA16(A, B, C) __builtin_amdgcn_mfma_f32_16x16x32_bf16((A), (B), (C), 0, 0, 0)

__global__ __launch_bounds__(512, 2) void gemm_pipe_kernel(
    const unsigned short* __restrict__ Ah, const unsigned short* __restrict__ Al,
    const unsigned short* __restrict__ Bh, const unsigned short* __restrict__ Bl,
    const float* __restrict__ bias2, float* __restrict__ out) {
  __shared__ float4 smem4[3 * BUFSZ / 16];
  char* smem = (char*)smem4;

  const int tid  = threadIdx.x;
  const int lane = tid & 63;
  const int wave = tid >> 6;
  const int wm   = wave >> 1;      // 0..3 : 64-row strip within 256
  const int wn   = wave & 1;       // 0..1 : 64-col strip within 128
  const int l15  = lane & 15;
  const int kl   = lane >> 4;
  const int bm = blockIdx.x;       // 32 strips of 256 rows
  const int bn = blockIdx.y;       // 16 strips of 128 cols

  // ---- per-lane staging sources (inverse-swizzled global granule) ----
  // Physical LDS granule for (inst i, wave, lane): p = i*512 + wave*64 + lane.
  // row = p>>2 -> rsub = wave*16 + (lane>>2); logical k-granule =
  // (p&3)^((p>>3)&3) = (lane&3)^((lane>>3)&3)  (i*512, wave*64 vanish mod 4).
  const int rsub = wave * 16 + (lane >> 2);                 // 0..127
  const int kg   = ((lane & 3) ^ ((lane >> 3) & 3)) * 8;    // element offset
  const unsigned short* sA0 = Ah + ((size_t)(bm * 256 +       rsub)) * DIM + kg;
  const unsigned short* sA1 = Ah + ((size_t)(bm * 256 + 128 + rsub)) * DIM + kg;
  const unsigned short* sA2 = Al + ((size_t)(bm * 256 +       rsub)) * DIM + kg;
  const unsigned short* sA3 = Al + ((size_t)(bm * 256 + 128 + rsub)) * DIM + kg;
  const unsigned short* sB0 = Bh + ((size_t)(bn * 128 +       rsub)) * DIM + kg;
  const unsigned short* sB1 = Bl + ((size_t)(bn * 128 +       rsub)) * DIM + kg;
  const unsigned wdst = wave * 1024;   // wave-uniform byte base within slot

  // ---- per-lane fragment read offset (matching swizzle) ----
  // A frag (mt,hl): byte = hl*16384 + (wm*64+mt*16)*64 + foff
  // B frag (nt,hl): byte = ABYTES + hl*8192 + (wn*64+nt*16)*64 + foff
  const int foff = l15 * 64 + ((kl * 16) ^ (((l15 >> 1) & 3) << 4));

  const f32x4_t vzero = {0.f, 0.f, 0.f, 0.f};
  f32x4_t acc[4][4];
#pragma unroll
  for (int i = 0; i < 4; ++i)
#pragma unroll
    for (int j = 0; j < 4; ++j) acc[i][j] = vzero;

  // ---- prologue: stage tile 0 -> buf0, tile 1 -> buf1 (6 loads each) ----
  GLDS(sA0,      0             + wdst);
  GLDS(sA1,      8192          + wdst);
  GLDS(sB0,      ABYTES        + wdst);
  GLDS(sA2,      16384         + wdst);
  GLDS(sA3,      24576         + wdst);
  GLDS(sB1,      ABYTES + 8192 + wdst);
  GLDS(sA0 + 32, BUFSZ + 0             + wdst);
  GLDS(sA1 + 32, BUFSZ + 8192          + wdst);
  GLDS(sB0 + 32, BUFSZ + ABYTES        + wdst);
  GLDS(sA2 + 32, BUFSZ + 16384         + wdst);
  GLDS(sA3 + 32, BUFSZ + 24576         + wdst);
  GLDS(sB1 + 32, BUFSZ + ABYTES + 8192 + wdst);

  // own tile-0 loads retired (6 newest = tile 1's), then collective barrier:
  // after this, ALL waves' tile-0 stores have landed in LDS.
  asm volatile("s_waitcnt vmcnt(6)" ::: "memory");
  asm volatile("s_barrier" ::: "memory");

#pragma unroll 1
  for (int t = 0; t < 64; ++t) {
    const unsigned bo = (unsigned)(t % 3) * BUFSZ;        // compute buffer
    const unsigned so = (unsigned)((t + 2) % 3) * BUFSZ;  // stage buffer
    const int ko = (t + 2) * 32;                          // stage src k-offset

    // ---- stage tile t+2 at iter top (WAR-safe: previous end-of-iter
    // barrier guarantees all waves finished reading this buf as tile t-1;
    // earliest issue = max HBM-latency cover under ~2 iters of MFMA) ----
    if (t < 62) {
      GLDS(sA0 + ko, so + 0             + wdst);
      GLDS(sA1 + ko, so + 8192          + wdst);
      GLDS(sB0 + ko, so + ABYTES        + wdst);
      GLDS(sA2 + ko, so + 16384         + wdst);
      GLDS(sA3 + ko, so + 24576         + wdst);
      GLDS(sB1 + ko, so + ABYTES + 8192 + wdst);
    }

    // ---- barrier-free compute: ds_reads + MFMA flow; waves drift so one
    // wave's MFMA hides another's LDS reads (separate pipes) ----
    bf16x8_t bh[4], bl[4], ah[2], al[2];
    const char* pB = smem + bo + ABYTES + wn * 4096 + foff;
#pragma unroll
    for (int nt = 0; nt < 4; ++nt) {
      bh[nt] = *(const bf16x8_t*)(pB + nt * 1024);
      bl[nt] = *(const bf16x8_t*)(pB + 8192 + nt * 1024);
    }
    const char* pA = smem + bo + wm * 4096 + foff;
    ah[0] = *(const bf16x8_t*)(pA);
    al[0] = *(const bf16x8_t*)(pA + 16384);
    ah[1] = *(const bf16x8_t*)(pA + 1024);
    al[1] = *(const bf16x8_t*)(pA + 16384 + 1024);

    __builtin_amdgcn_s_setprio(1);
#pragma unroll
    for (int i = 0; i < 2; ++i)
#pragma unroll
      for (int nt = 0; nt < 4; ++nt) {
        acc[i][nt] = MFMA16(ah[i], bh[nt], acc[i][nt]);
        acc[i][nt] = MFMA16(ah[i], bl[nt], acc[i][nt]);
        acc[i][nt] = MFMA16(al[i], bh[nt], acc[i][nt]);
      }
    __builtin_amdgcn_s_setprio(0);

    bf16x8_t ah2[2], al2[2];
    ah2[0] = *(const bf16x8_t*)(pA + 2048);
    al2[0] = *(const bf16x8_t*)(pA + 16384 + 2048);
    ah2[1] = *(const bf16x8_t*)(pA + 3072);
    al2[1] = *(const bf16x8_t*)(pA + 16384 + 3072);

    __builtin_amdgcn_s_setprio(1);
#pragma unroll
    for (int i = 0; i < 2; ++i)
#pragma unroll
      for (int nt = 0; nt < 4; ++nt) {
        acc[2 + i][nt] = MFMA16(ah2[i], bh[nt], acc[2 + i][nt]);
        acc[2 + i][nt] = MFMA16(ah2[i], bl[nt], acc[2 + i][nt]);
        acc[2 + i][nt] = MFMA16(al2[i], bh[nt], acc[2 + i][nt]);
      }
    __builtin_amdgcn_s_setprio(0);

    // ---- single end-of-iter sync: each wave retires its OWN tile-(t+1)
    // loads (6 newest outstanding = tile t+2's), then collective barrier =>
    // (RAW) all waves' tile-t+1 stores landed before anyone's iter-t+1
    // ds_reads; (WAR) all waves' iter-t ds_reads done before anyone's
    // iter-t+1 GLDS into buf t%3. Never drains to 0 while staging. ----
    if (t < 62)       { asm volatile("s_waitcnt vmcnt(6)" ::: "memory"); }
    else if (t == 62) { asm volatile("s_waitcnt vmcnt(0)" ::: "memory"); }
    if (t < 63)       { asm volatile("s_barrier" ::: "memory"); }
  }

  // ---- epilogue: C/D layout col = lane&15, row = (lane>>4)*4 + reg ----
  const int orow0 = bm * 256 + wm * 64;
  const int ocol0 = bn * 128 + wn * 64;
#pragma unroll
  for (int j = 0; j < 4; ++j) {
    const int col = ocol0 + j * 16 + l15;
    const float b2 = bias2[col];
#pragma unroll
    for (int i = 0; i < 4; ++i) {
      const int row = orow0 + i * 16 + kl * 4;
#pragma unroll
      for (int r = 0; r < 4; ++r) {
        float z = acc[i][j][r] + b2;
        // tanh(z) = 1 - 2/(exp(2z)+1)
        float e = __expf(2.0f * z);
        out[(size_t)(row + r) * DIM + col] = 1.0f - 2.0f / (e + 1.0f);
      }
    }
  }
}

// ============================================================================
extern "C" void kernel_launch(void* const* d_in, const int* in_sizes, int n_in,
                              void* d_out, int out_size, void* d_ws, size_t ws_size,
                              hipStream_t stream) {
  const float* x   = (const float*)d_in[0];
  const float* hdw = (const float*)d_in[1];
  const float* W   = (const float*)d_in[2];
  const float* b   = (const float*)d_in[3];
  float* out = (float*)d_out;

  // workspace layout (~80.01 MB)
  char* ws = (char*)d_ws;
  unsigned short* xhi  = (unsigned short*)ws;                    // 32 MB
  unsigned short* xlo  = xhi + (size_t)BATCH * DIM;              // 32 MB
  unsigned short* wThi = xlo + (size_t)BATCH * DIM;              // 8 MB
  unsigned short* wTlo = wThi + (size_t)DIM * DIM;               // 8 MB
  float*          bias2 = (float*)(wTlo + (size_t)DIM * DIM);    // 8 KB

  prep_fused_kernel<<<12296, 256, 0, stream>>>(
      x, hdw, W, b, bias2, xhi, xlo, wThi, wTlo);
  gemm_pipe_kernel<<<dim3(BATCH / 256, DIM / 128), 512, 0, stream>>>(
      xhi, xlo, wThi, wTlo, bias2, out);
}

// Round 10
// 333.800 us; speedup vs baseline: 1.0899x; 1.0659x over previous
//
#include <hip/hip_runtime.h>

#define BATCH 8192
#define DIM   2048   // IN_DIM == OUT_DIM
#define DEPTH 5

// ============================================================================
// r8 GEMM geometry: block tile 256(M) x 256(N), BK=32, 512 threads = 8 waves
// (4 wm x 2 wn), wave tile 64x128 = 4x8 frags of 16x16x32 bf16 MFMA, bf16x3
// triple (hh, hl, lh) -> 96 MFMA / wave / K-tile (768/CU-iter, floor 3726 cyc).
//
// WHY (r7 post-mortem): r7 measured 3637 cyc/iter vs 1863 MFMA floor with
// MfmaUtil 49%, bank-conflicts 0. Binding constraint = LDS BANDWIDTH:
// 176 KB/CU-iter through ~85-128 B/cyc = 1400-2100 cyc, ~= MFMA floor ->
// pipes couldn't hide each other. This tile doubles FLOPs per LDS byte:
// 256 KB per 3726-cyc iter = 69 B/cyc demand < 85 sustainable.
//
// LDS: 2-deep x 64 KB buffers (A [hl2][256r][32k] 32 KB @0, B same @32 KB).
// Swizzle (T2, carried from r4/r7, measured 0 conflicts): phys byte =
// logical ^ (((row>>1)&3)<<4); applied via inverse-swizzled GLOBAL source
// granule (rule 21) + swizzled ds_read offset. Row bases ≡ 0 mod 16 so the
// read-side XOR depends only on l15 -- formula unchanged.
//
// Pipeline: stage tile t+1 (8 GLDS) at iter top into buf (t+1)&1 (WAR-safe:
// that buf's tile t-1 reads all completed before the end-of-iter-(t-1)
// barrier). End of iter: vmcnt(0) -- zero-cost, the loads had a full iter
// (~3700 cyc >> 900 HBM latency) -- + one s_barrier. setprio around MFMA.
// ============================================================================

#define BUFSZ  65536
#define ABYTES 32768

typedef short bf16x8_t __attribute__((ext_vector_type(8)));
typedef float f32x4_t  __attribute__((ext_vector_type(4)));

// ---- bf16 split helpers (RNE, bit-manip) ----
__device__ __forceinline__ unsigned short f2bf(float f) {
  unsigned u = __float_as_uint(f);
  u += 0x7fffu + ((u >> 16) & 1u);
  return (unsigned short)(u >> 16);
}
__device__ __forceinline__ float bf2f(unsigned short h) {
  return __uint_as_float(((unsigned)h) << 16);
}

// ============================================================================
// Fused prep (one dispatch) -- unchanged (verified r4/r7):
//  blocks [0, 8192)      : split x -> xhi/xlo, row-major [8192][2048] bf16
//  blocks [8192, 12288)  : W (KxN) -> transpose+split -> whi/wlo [N][K] bf16
//  blocks [12288, 12296) : bias2[j] = b[j] + (1/2048)*prod_d cos(hdw[d,j,0])^2
// ============================================================================
__global__ void prep_fused_kernel(const float* __restrict__ x,
                                  const float* __restrict__ hdw,
                                  const float* __restrict__ W,
                                  const float* __restrict__ bias,
                                  float* __restrict__ bias2,
                                  unsigned short* __restrict__ xhi,
                                  unsigned short* __restrict__ xlo,
                                  unsigned short* __restrict__ whi,
                                  unsigned short* __restrict__ wlo) {
  __shared__ float tile[32][33];
  const int b = blockIdx.x;
  const int tid = threadIdx.x;

  if (b < 8192) {  // ---- split x, row-major ----
    size_t g = (size_t)b * 256 + tid;       // 8-elem chunk id
    const float4* xp = (const float4*)(x + g * 8);
    float4 v0 = xp[0], v1 = xp[1];
    float v[8] = {v0.x, v0.y, v0.z, v0.w, v1.x, v1.y, v1.z, v1.w};
    bf16x8_t h, lo;
#pragma unroll
    for (int j = 0; j < 8; ++j) {
      unsigned short hj = f2bf(v[j]);
      h[j] = (short)hj;
      lo[j] = (short)f2bf(v[j] - bf2f(hj));
    }
    ((bf16x8_t*)xhi)[g] = h;
    ((bf16x8_t*)xlo)[g] = lo;
  } else if (b < 12288) {  // ---- transpose + split W -> [N][K] ----
    const int t = b - 8192;          // 4096 tiles of 32x32
    const int k0 = (t >> 6) * 32;
    const int n0 = (t & 63) * 32;
    const int tx = tid & 31;   // n within tile
    const int ty = tid >> 5;   // k within tile (8 rows/iter)
#pragma unroll
    for (int r = 0; r < 32; r += 8)
      tile[ty + r][tx] = W[(size_t)(k0 + ty + r) * DIM + n0 + tx];
    __syncthreads();
    const int n = tid >> 3;          // 0..31
    const int kq = (tid & 7) * 4;    // 0..28
    ushort4 hv, lv;
    float vv0 = tile[kq + 0][n], vv1 = tile[kq + 1][n];
    float vv2 = tile[kq + 2][n], vv3 = tile[kq + 3][n];
    hv.x = f2bf(vv0); lv.x = f2bf(vv0 - bf2f(hv.x));
    hv.y = f2bf(vv1); lv.y = f2bf(vv1 - bf2f(hv.y));
    hv.z = f2bf(vv2); lv.z = f2bf(vv2 - bf2f(hv.z));
    hv.w = f2bf(vv3); lv.w = f2bf(vv3 - bf2f(hv.w));
    const size_t o = (size_t)(n0 + n) * DIM + k0 + kq;
    *(ushort4*)(whi + o) = hv;
    *(ushort4*)(wlo + o) = lv;
  } else {  // ---- bias2 (scan preserves axis-1 uniformity -> rolls cancel) ----
    int j = (b - 12288) * 256 + tid;
    float p = 1.0f;
#pragma unroll
    for (int d = 0; d < DEPTH; ++d)
      p *= cosf(hdw[(size_t)d * DIM * DIM + (size_t)j * DIM]);
    bias2[j] = bias[j] + p * p * (1.0f / 2048.0f);
  }
}

// ---- async global->LDS, 16B per lane, LDS dest = wave-uniform base + lane*16
#define GLDS(SRC, OFF)                                                         \
  __builtin_amdgcn_global_load_lds(                                            \
      (const __attribute__((address_space(1))) unsigned int*)(SRC),            \
      (__attribute__((address_space(3))) unsigned int*)(smem + (OFF)), 16, 0, 0)

#define MFMA16(A, B, C) __builtin_amdgcn_mfma_f32_16x16x32_bf16((A), (B), (C), 0, 0, 0)

// stage one 64 KB tile (k-element offset KO) into buffer at byte SO:
// 8 GLDS x 512 threads x 16 B; instr i covers 128 rows (halves of A/B, hi/lo)
#define STAGE(KO, SO)                                                          \
  do {                                                                         \
    GLDS(sAh + (KO),             (SO) + 0              + wdst);                \
    GLDS(sAh + 128 * DIM + (KO), (SO) + 8192           + wdst);                \
    GLDS(sAl + (KO),             (SO) + 16384          + wdst);                \
    GLDS(sAl + 128 * DIM + (KO), (SO) + 24576          + wdst);                \
    GLDS(sBh + (KO),             (SO) + ABYTES + 0     + wdst);                \
    GLDS(sBh + 128 * DIM + (KO), (SO) + ABYTES + 8192  + wdst);                \
    GLDS(sBl + (KO),             (SO) + ABYTES + 16384 + wdst);                \
    GLDS(sBl + 128 * DIM + (KO), (SO) + ABYTES + 24576 + wdst);                \
  } while (0)

__global__ __launch_bounds__(512, 2) void gemm_pipe_kernel(
    const unsigned short* __restrict__ Ah, const unsigned short* __restrict__ Al,
    const unsigned short* __restrict__ Bh, const unsigned short* __restrict__ Bl,
    const float* __restrict__ bias2, float* __restrict__ out) {
  __shared__ float4 smem4[2 * BUFSZ / 16];
  char* smem = (char*)smem4;

  const int tid  = threadIdx.x;
  const int lane = tid & 63;
  const int wave = tid >> 6;
  const int wm   = wave >> 1;      // 0..3 : 64-row strip within 256
  const int wn   = wave & 1;       // 0..1 : 128-col strip within 256
  const int l15  = lane & 15;
  const int kl   = lane >> 4;
  const int bm = blockIdx.x;       // 32 strips of 256 rows
  const int bn = blockIdx.y;       // 8 strips of 256 cols

  // ---- per-lane staging sources (inverse-swizzled global granule) ----
  // Per GLDS instr: phys granule g = wave*64+lane -> row g>>2 = wave*16+(lane>>2),
  // col granule g&3; stored logical k-granule = (g&3)^((row>>1)&3)
  // = (lane&3)^((lane>>3)&3)  (wave*16>>1 = wave*8 ≡ 0 mod 4).
  const int rsub = wave * 16 + (lane >> 2);                 // 0..127
  const int kg   = ((lane & 3) ^ ((lane >> 3) & 3)) * 8;    // element offset
  const unsigned short* sAh = Ah + ((size_t)(bm * 256 + rsub)) * DIM + kg;
  const unsigned short* sAl = Al + ((size_t)(bm * 256 + rsub)) * DIM + kg;
  const unsigned short* sBh = Bh + ((size_t)(bn * 256 + rsub)) * DIM + kg;
  const unsigned short* sBl = Bl + ((size_t)(bn * 256 + rsub)) * DIM + kg;
  const unsigned wdst = wave * 1024;   // wave-uniform byte base per instr

  // ---- per-lane fragment read offset (matching swizzle) ----
  // frag row base ≡ 0 mod 16 -> XOR term depends only on l15:
  const int foff = l15 * 64 + ((kl * 16) ^ (((l15 >> 1) & 3) << 4));

  const f32x4_t vzero = {0.f, 0.f, 0.f, 0.f};
  f32x4_t acc[4][8];
#pragma unroll
  for (int i = 0; i < 4; ++i)
#pragma unroll
    for (int j = 0; j < 8; ++j) acc[i][j] = vzero;

  // ---- prologue: stage tile 0 -> buf0, full drain (one-time cost) ----
  STAGE(0, 0);
  asm volatile("s_waitcnt vmcnt(0)" ::: "memory");
  asm volatile("s_barrier" ::: "memory");

#pragma unroll 1
  for (int t = 0; t < 64; ++t) {
    const unsigned bo = (unsigned)(t & 1) * BUFSZ;   // compute buffer
    const unsigned so = bo ^ BUFSZ;                  // stage buffer

    // ---- stage tile t+1 at iter top (WAR-safe: buf so's tile t-1 reads
    // all completed before the end-of-iter-(t-1) barrier) ----
    if (t < 63) {
      const int ko = (t + 1) * 32;
      STAGE(ko, so);
    }

    // ---- A fragments (live across both B halves) ----
    const char* pA = smem + bo + wm * 4096 + foff;          // wm*64 rows *64B
    bf16x8_t ah[4], al[4];
#pragma unroll
    for (int mt = 0; mt < 4; ++mt) {
      ah[mt] = *(const bf16x8_t*)(pA + mt * 1024);
      al[mt] = *(const bf16x8_t*)(pA + 16384 + mt * 1024);
    }

    const char* pB = smem + bo + ABYTES + wn * 8192 + foff; // wn*128 rows *64B

    // ---- B half 0 : nt 0..3 ----
    {
      bf16x8_t bh[4], bl[4];
#pragma unroll
      for (int nt = 0; nt < 4; ++nt) {
        bh[nt] = *(const bf16x8_t*)(pB + nt * 1024);
        bl[nt] = *(const bf16x8_t*)(pB + 16384 + nt * 1024);
      }
      __builtin_amdgcn_s_setprio(1);
#pragma unroll
      for (int mt = 0; mt < 4; ++mt)
#pragma unroll
        for (int nt = 0; nt < 4; ++nt) {
          acc[mt][nt] = MFMA16(ah[mt], bh[nt], acc[mt][nt]);
          acc[mt][nt] = MFMA16(ah[mt], bl[nt], acc[mt][nt]);
          acc[mt][nt] = MFMA16(al[mt], bh[nt], acc[mt][nt]);
        }
      __builtin_amdgcn_s_setprio(0);
    }

    // ---- B half 1 : nt 4..7 ----
    {
      bf16x8_t bh[4], bl[4];
#pragma unroll
      for (int nt = 0; nt < 4; ++nt) {
        bh[nt] = *(const bf16x8_t*)(pB + 4096 + nt * 1024);
        bl[nt] = *(const bf16x8_t*)(pB + 16384 + 4096 + nt * 1024);
      }
      __builtin_amdgcn_s_setprio(1);
#pragma unroll
      for (int mt = 0; mt < 4; ++mt)
#pragma unroll
        for (int nt = 0; nt < 4; ++nt) {
          acc[mt][4 + nt] = MFMA16(ah[mt], bh[nt], acc[mt][4 + nt]);
          acc[mt][4 + nt] = MFMA16(ah[mt], bl[nt], acc[mt][4 + nt]);
          acc[mt][4 + nt] = MFMA16(al[mt], bh[nt], acc[mt][4 + nt]);
        }
      __builtin_amdgcn_s_setprio(0);
    }

    // ---- end-of-iter sync: tile t+1's 8 loads are the only outstanding;
    // they were issued a full iteration ago (~3700 cyc >> 900 HBM latency)
    // so this wait is ~free. Barrier makes it collective (RAW) and fences
    // next iter's staging (WAR). ----
    if (t < 63) {
      asm volatile("s_waitcnt vmcnt(0)" ::: "memory");
      asm volatile("s_barrier" ::: "memory");
    }
  }

  // ---- epilogue: C/D layout col = lane&15, row = (lane>>4)*4 + reg ----
  const int orow0 = bm * 256 + wm * 64;
  const int ocol0 = bn * 256 + wn * 128;
#pragma unroll
  for (int nt = 0; nt < 8; ++nt) {
    const int col = ocol0 + nt * 16 + l15;
    const float b2 = bias2[col];
#pragma unroll
    for (int mt = 0; mt < 4; ++mt) {
      const int row = orow0 + mt * 16 + kl * 4;
#pragma unroll
      for (int r = 0; r < 4; ++r) {
        float z = acc[mt][nt][r] + b2;
        // tanh(z) = 1 - 2/(exp(2z)+1)
        float e = __expf(2.0f * z);
        out[(size_t)(row + r) * DIM + col] = 1.0f - 2.0f / (e + 1.0f);
      }
    }
  }
}

// ============================================================================
extern "C" void kernel_launch(void* const* d_in, const int* in_sizes, int n_in,
                              void* d_out, int out_size, void* d_ws, size_t ws_size,
                              hipStream_t stream) {
  const float* x   = (const float*)d_in[0];
  const float* hdw = (const float*)d_in[1];
  const float* W   = (const float*)d_in[2];
  const float* b   = (const float*)d_in[3];
  float* out = (float*)d_out;

  // workspace layout (~80.01 MB)
  char* ws = (char*)d_ws;
  unsigned short* xhi  = (unsigned short*)ws;                    // 32 MB
  unsigned short* xlo  = xhi + (size_t)BATCH * DIM;              // 32 MB
  unsigned short* wThi = xlo + (size_t)BATCH * DIM;              // 8 MB
  unsigned short* wTlo = wThi + (size_t)DIM * DIM;               // 8 MB
  float*          bias2 = (float*)(wTlo + (size_t)DIM * DIM);    // 8 KB

  prep_fused_kernel<<<12296, 256, 0, stream>>>(
      x, hdw, W, b, bias2, xhi, xlo, wThi, wTlo);
  gemm_pipe_kernel<<<dim3(BATCH / 256, DIM / 256), 512, 0, stream>>>(
      xhi, xlo, wThi, wTlo, bias2, out);
}

// Round 13
// 326.824 us; speedup vs baseline: 1.1131x; 1.0213x over previous
//
#include <hip/hip_runtime.h>

#define BATCH 8192
#define DIM   2048   // IN_DIM == OUT_DIM
#define DEPTH 5

// ============================================================================
// r10: 256x256 tile (r8-verified layout) + register quarter-pipeline.
//
// r8 post-mortem: iter = 6263 cyc ~= MFMA 3726 + LDS 2600 -> ADDITIVE pipes.
// Compiler clusters all 24 ds_reads then all 96 MFMAs; barrier keeps waves in
// phase -> CU-wide read-storm (MFMA idle) then MFMA-storm (LDS idle).
//
// Fix: 4 quarters (2 nt each). Per quarter: issue next quarter's 4 ds_reads,
// then 24 MFMAs on the previous quarter's regs -> each read burst hides under
// an independent ~470-cyc MFMA cluster. Two alternating STATIC reg sets
// (Bc/Bn, rule 20). Cross-iter seam: mid-iter lgkm0+vmcnt0+barrier after q2;
// then read B-quarter0(t+1) from the just-landed buffer BEFORE q3(t) MFMAs
// (q3 is reg-only); A(t+1) read after q3 (~150 cyc exposed).
//
// Hazards (one barrier/iter, after q2):
//  RAW tile t+1: staged at top of t, vmcnt(0)+barrier before its first reads.
//  WAR stage(t+2)->buf t&1 at top of t+1: its readers are q0-q2(t) quarter
//   reads (lgkm0 before the mid-t barrier) and A(t)/B0(t) reads from end of
//   t-1 (lgkm-drained before q0(t) MFMA, which precedes the mid-t barrier).
//   Every wave passes the mid-t barrier after draining -> safe cross-wave.
//  vmcnt ledger: only stage(t+1)'s 8 loads outstanding at mid-iter drain;
//   issued ~3000 cyc earlier (>> 900-cyc HBM miss) -> wait ~free.
// ============================================================================

#define BUFSZ  65536
#define ABYTES 32768

typedef short bf16x8_t __attribute__((ext_vector_type(8)));
typedef float f32x4_t  __attribute__((ext_vector_type(4)));

// ---- bf16 split helpers (RNE, bit-manip) ----
__device__ __forceinline__ unsigned short f2bf(float f) {
  unsigned u = __float_as_uint(f);
  u += 0x7fffu + ((u >> 16) & 1u);
  return (unsigned short)(u >> 16);
}
__device__ __forceinline__ float bf2f(unsigned short h) {
  return __uint_as_float(((unsigned)h) << 16);
}

// ============================================================================
// Fused prep (one dispatch) -- unchanged (verified r4/r7/r8).
// ============================================================================
__global__ void prep_fused_kernel(const float* __restrict__ x,
                                  const float* __restrict__ hdw,
                                  const float* __restrict__ W,
                                  const float* __restrict__ bias,
                                  float* __restrict__ bias2,
                                  unsigned short* __restrict__ xhi,
                                  unsigned short* __restrict__ xlo,
                                  unsigned short* __restrict__ whi,
                                  unsigned short* __restrict__ wlo) {
  __shared__ float tile[32][33];
  const int b = blockIdx.x;
  const int tid = threadIdx.x;

  if (b < 8192) {  // ---- split x, row-major ----
    size_t g = (size_t)b * 256 + tid;       // 8-elem chunk id
    const float4* xp = (const float4*)(x + g * 8);
    float4 v0 = xp[0], v1 = xp[1];
    float v[8] = {v0.x, v0.y, v0.z, v0.w, v1.x, v1.y, v1.z, v1.w};
    bf16x8_t h, lo;
#pragma unroll
    for (int j = 0; j < 8; ++j) {
      unsigned short hj = f2bf(v[j]);
      h[j] = (short)hj;
      lo[j] = (short)f2bf(v[j] - bf2f(hj));
    }
    ((bf16x8_t*)xhi)[g] = h;
    ((bf16x8_t*)xlo)[g] = lo;
  } else if (b < 12288) {  // ---- transpose + split W -> [N][K] ----
    const int t = b - 8192;          // 4096 tiles of 32x32
    const int k0 = (t >> 6) * 32;
    const int n0 = (t & 63) * 32;
    const int tx = tid & 31;   // n within tile
    const int ty = tid >> 5;   // k within tile (8 rows/iter)
#pragma unroll
    for (int r = 0; r < 32; r += 8)
      tile[ty + r][tx] = W[(size_t)(k0 + ty + r) * DIM + n0 + tx];
    __syncthreads();
    const int n = tid >> 3;          // 0..31
    const int kq = (tid & 7) * 4;    // 0..28
    ushort4 hv, lv;
    float vv0 = tile[kq + 0][n], vv1 = tile[kq + 1][n];
    float vv2 = tile[kq + 2][n], vv3 = tile[kq + 3][n];
    hv.x = f2bf(vv0); lv.x = f2bf(vv0 - bf2f(hv.x));
    hv.y = f2bf(vv1); lv.y = f2bf(vv1 - bf2f(hv.y));
    hv.z = f2bf(vv2); lv.z = f2bf(vv2 - bf2f(hv.z));
    hv.w = f2bf(vv3); lv.w = f2bf(vv3 - bf2f(hv.w));
    const size_t o = (size_t)(n0 + n) * DIM + k0 + kq;
    *(ushort4*)(whi + o) = hv;
    *(ushort4*)(wlo + o) = lv;
  } else {  // ---- bias2 (scan preserves axis-1 uniformity -> rolls cancel) ----
    int j = (b - 12288) * 256 + tid;
    float p = 1.0f;
#pragma unroll
    for (int d = 0; d < DEPTH; ++d)
      p *= cosf(hdw[(size_t)d * DIM * DIM + (size_t)j * DIM]);
    bias2[j] = bias[j] + p * p * (1.0f / 2048.0f);
  }
}

// ---- async global->LDS, 16B per lane, LDS dest = wave-uniform base + lane*16
#define GLDS(SRC, OFF)                                                         \
  __builtin_amdgcn_global_load_lds(                                            \
      (const __attribute__((address_space(1))) unsigned int*)(SRC),            \
      (__attribute__((address_space(3))) unsigned int*)(smem + (OFF)), 16, 0, 0)

#define MFMA16(A, B, C) __builtin_amdgcn_mfma_f32_16x16x32_bf16((A), (B), (C), 0, 0, 0)

// stage one 64 KB tile (k-element offset KO) into buffer at byte SO
#define STAGE(KO, SO)                                                          \
  do {                                                                         \
    GLDS(sAh + (KO),             (SO) + 0              + wdst);                \
    GLDS(sAh + 128 * DIM + (KO), (SO) + 8192           + wdst);                \
    GLDS(sAl + (KO),             (SO) + 16384          + wdst);                \
    GLDS(sAl + 128 * DIM + (KO), (SO) + 24576          + wdst);                \
    GLDS(sBh + (KO),             (SO) + ABYTES + 0     + wdst);                \
    GLDS(sBh + 128 * DIM + (KO), (SO) + ABYTES + 8192  + wdst);                \
    GLDS(sBl + (KO),             (SO) + ABYTES + 16384 + wdst);                \
    GLDS(sBl + 128 * DIM + (KO), (SO) + ABYTES + 24576 + wdst);                \
  } while (0)

// read one B quarter (nt = NT, NT+1) from buffer base PB into 4 named regs
#define READ_BQ(PB, NT, H0, L0, H1, L1)                                        \
  do {                                                                         \
    H0 = *(const bf16x8_t*)((PB) + (NT) * 1024);                               \
    L0 = *(const bf16x8_t*)((PB) + 16384 + (NT) * 1024);                       \
    H1 = *(const bf16x8_t*)((PB) + ((NT) + 1) * 1024);                         \
    L1 = *(const bf16x8_t*)((PB) + 16384 + ((NT) + 1) * 1024);                 \
  } while (0)

// 24 MFMA: quarter with B regs (H0,L0,H1,L1) into acc columns C0, C0+1
#define QMFMA(H0, L0, H1, L1, C0)                                              \
  do {                                                                         \
    __builtin_amdgcn_s_setprio(1);                                             \
    _Pragma("unroll")                                                          \
    for (int mt = 0; mt < 4; ++mt) {                                           \
      acc[mt][C0]     = MFMA16(A_h[mt], H0, acc[mt][C0]);                      \
      acc[mt][C0]     = MFMA16(A_h[mt], L0, acc[mt][C0]);                      \
      acc[mt][C0]     = MFMA16(A_l[mt], H0, acc[mt][C0]);                      \
      acc[mt][C0 + 1] = MFMA16(A_h[mt], H1, acc[mt][C0 + 1]);                  \
      acc[mt][C0 + 1] = MFMA16(A_h[mt], L1, acc[mt][C0 + 1]);                  \
      acc[mt][C0 + 1] = MFMA16(A_l[mt], H1, acc[mt][C0 + 1]);                  \
    }                                                                          \
    __builtin_amdgcn_s_setprio(0);                                             \
  } while (0)

__global__ __launch_bounds__(512, 2) void gemm_pipe_kernel(
    const unsigned short* __restrict__ Ah, const unsigned short* __restrict__ Al,
    const unsigned short* __restrict__ Bh, const unsigned short* __restrict__ Bl,
    const float* __restrict__ bias2, float* __restrict__ out) {
  __shared__ float4 smem4[2 * BUFSZ / 16];
  char* smem = (char*)smem4;

  const int tid  = threadIdx.x;
  const int lane = tid & 63;
  const int wave = tid >> 6;
  const int wm   = wave >> 1;      // 0..3 : 64-row strip within 256
  const int wn   = wave & 1;       // 0..1 : 128-col strip within 256
  const int l15  = lane & 15;
  const int kl   = lane >> 4;
  const int bm = blockIdx.x;       // 32 strips of 256 rows
  const int bn = blockIdx.y;       // 8 strips of 256 cols

  // ---- per-lane staging sources (inverse-swizzled global granule) ----
  const int rsub = wave * 16 + (lane >> 2);                 // 0..127
  const int kg   = ((lane & 3) ^ ((lane >> 3) & 3)) * 8;    // element offset
  const unsigned short* sAh = Ah + ((size_t)(bm * 256 + rsub)) * DIM + kg;
  const unsigned short* sAl = Al + ((size_t)(bm * 256 + rsub)) * DIM + kg;
  const unsigned short* sBh = Bh + ((size_t)(bn * 256 + rsub)) * DIM + kg;
  const unsigned short* sBl = Bl + ((size_t)(bn * 256 + rsub)) * DIM + kg;
  const unsigned wdst = wave * 1024;   // wave-uniform byte base per instr

  // ---- per-lane fragment read offset (matching swizzle) ----
  const int foff = l15 * 64 + ((kl * 16) ^ (((l15 >> 1) & 3) << 4));

  const f32x4_t vzero = {0.f, 0.f, 0.f, 0.f};
  f32x4_t acc[4][8];
#pragma unroll
  for (int i = 0; i < 4; ++i)
#pragma unroll
    for (int j = 0; j < 8; ++j) acc[i][j] = vzero;

  // fragment registers: A (current tile), B ping-pong quarter sets
  bf16x8_t A_h[4], A_l[4];
  bf16x8_t Bc_h0, Bc_l0, Bc_h1, Bc_l1;   // "current" set
  bf16x8_t Bn_h0, Bn_l0, Bn_h1, Bn_l1;   // "next" set

  // ---- prologue: stage tile 0 -> buf0, drain, preload A(0) + quarter0 ----
  STAGE(0, 0);
  asm volatile("s_waitcnt vmcnt(0)" ::: "memory");
  asm volatile("s_barrier" ::: "memory");
  {
    const char* pA0 = smem + wm * 4096 + foff;
#pragma unroll
    for (int mt = 0; mt < 4; ++mt) {
      A_h[mt] = *(const bf16x8_t*)(pA0 + mt * 1024);
      A_l[mt] = *(const bf16x8_t*)(pA0 + 16384 + mt * 1024);
    }
    const char* pB0 = smem + ABYTES + wn * 8192 + foff;
    READ_BQ(pB0, 0, Bc_h0, Bc_l0, Bc_h1, Bc_l1);
  }

#pragma unroll 1
  for (int t = 0; t < 64; ++t) {
    const unsigned bo = (unsigned)(t & 1) * BUFSZ;   // compute buffer
    const unsigned so = bo ^ BUFSZ;                  // stage buffer
    const char* pB = smem + bo + ABYTES + wn * 8192 + foff;

    // ---- stage tile t+1 at iter top ----
    if (t < 63) {
      const int ko = (t + 1) * 32;
      STAGE(ko, so);
    }

    // q0: read quarter1 -> Bn ; MFMA quarter0 (Bc) -> cols 0,1
    READ_BQ(pB, 2, Bn_h0, Bn_l0, Bn_h1, Bn_l1);
    QMFMA(Bc_h0, Bc_l0, Bc_h1, Bc_l1, 0);

    // q1: read quarter2 -> Bc ; MFMA quarter1 (Bn) -> cols 2,3
    READ_BQ(pB, 4, Bc_h0, Bc_l0, Bc_h1, Bc_l1);
    QMFMA(Bn_h0, Bn_l0, Bn_h1, Bn_l1, 2);

    // q2: read quarter3 -> Bn ; MFMA quarter2 (Bc) -> cols 4,5
    READ_BQ(pB, 6, Bn_h0, Bn_l0, Bn_h1, Bn_l1);
    QMFMA(Bc_h0, Bc_l0, Bc_h1, Bc_l1, 4);

    // ---- mid-iter sync: all tile-t LDS reads issued above are drained
    // (lgkm0), tile t+1's staging landed (vmcnt0), then barrier. ----
    asm volatile("s_waitcnt lgkmcnt(0)" ::: "memory");
    if (t < 63) { asm volatile("s_waitcnt vmcnt(0)" ::: "memory"); }
    asm volatile("s_barrier" ::: "memory");

    // read quarter0(t+1) from the just-landed buffer (Bc is dead) --
    // overlaps with q3's reg-only MFMAs below
    if (t < 63) {
      const char* pBn = smem + so + ABYTES + wn * 8192 + foff;
      READ_BQ(pBn, 0, Bc_h0, Bc_l0, Bc_h1, Bc_l1);
    }

    // q3: MFMA quarter3 (Bn) -> cols 6,7
    QMFMA(Bn_h0, Bn_l0, Bn_h1, Bn_l1, 6);

    // read A(t+1) (A regs dead after q3) -- ~150 cyc exposed at seam
    if (t < 63) {
      const char* pAn = smem + so + wm * 4096 + foff;
#pragma unroll
      for (int mt = 0; mt < 4; ++mt) {
        A_h[mt] = *(const bf16x8_t*)(pAn + mt * 1024);
        A_l[mt] = *(const bf16x8_t*)(pAn + 16384 + mt * 1024);
      }
    }
  }

  // ---- epilogue: C/D layout col = lane&15, row = (lane>>4)*4 + reg ----
  const int orow0 = bm * 256 + wm * 64;
  const int ocol0 = bn * 256 + wn * 128;
#pragma unroll
  for (int nt = 0; nt < 8; ++nt) {
    const int col = ocol0 + nt * 16 + l15;
    const float b2 = bias2[col];
#pragma unroll
    for (int mt = 0; mt < 4; ++mt) {
      const int row = orow0 + mt * 16 + kl * 4;
#pragma unroll
      for (int r = 0; r < 4; ++r) {
        float z = acc[mt][nt][r] + b2;
        // tanh(z) = 1 - 2/(exp(2z)+1)
        float e = __expf(2.0f * z);
        out[(size_t)(row + r) * DIM + col] = 1.0f - 2.0f / (e + 1.0f);
      }
    }
  }
}

// ============================================================================
extern "C" void kernel_launch(void* const* d_in, const int* in_sizes, int n_in,
                              void* d_out, int out_size, void* d_ws, size_t ws_size,
                              hipStream_t stream) {
  const float* x   = (const float*)d_in[0];
  const float* hdw = (const float*)d_in[1];
  const float* W   = (const float*)d_in[2];
  const float* b   = (const float*)d_in[3];
  float* out = (float*)d_out;

  // workspace layout (~80.01 MB)
  char* ws = (char*)d_ws;
  unsigned short* xhi  = (unsigned short*)ws;                    // 32 MB
  unsigned short* xlo  = xhi + (size_t)BATCH * DIM;              // 32 MB
  unsigned short* wThi = xlo + (size_t)BATCH * DIM;              // 8 MB
  unsigned short* wTlo = wThi + (size_t)DIM * DIM;               // 8 MB
  float*          bias2 = (float*)(wTlo + (size_t)DIM * DIM);    // 8 KB

  prep_fused_kernel<<<12296, 256, 0, stream>>>(
      x, hdw, W, b, bias2, xhi, xlo, wThi, wTlo);
  gemm_pipe_kernel<<<dim3(BATCH / 256, DIM / 256), 512, 0, stream>>>(
      xhi, xlo, wThi, wTlo, bias2, out);
}